// Round 1
// baseline (13587.506 us; speedup 1.0000x reference)
//
#include <hip/hip_runtime.h>

// ---------------- problem constants ----------------
constexpr int B = 64, L = 512, E = 256, H = 512;
constexpr int ROWS = 4 * H;      // 2048 gate-rows (unit*4 + gate interleave)
constexpr int K    = E + H;      // 768
constexpr int K4   = K / 4;      // 192

// ---------------- ws layout (in floats) ----------------
constexpr size_t OFF_WT4  = 0;
constexpr size_t SZ_WT4   = (size_t)K4 * ROWS * 4;      // float4[K4][ROWS]
constexpr size_t OFF_BI   = OFF_WT4 + SZ_WT4;           // interleaved biases [ROWS]
constexpr size_t SZ_BI    = ROWS;
constexpr size_t OFF_HB   = OFF_BI + SZ_BI;             // h dbuf [2][B][H] (LLC-coherent traffic)
constexpr size_t SZ_HB    = (size_t)2 * B * H;
constexpr size_t OFF_REP  = OFF_HB + SZ_HB;             // rep accumulator [B][H]
constexpr size_t SZ_REP   = (size_t)B * H;
constexpr size_t OFF_FLG  = OFF_REP + SZ_REP;           // flags [8 sg][32 rg], 128B apart
constexpr size_t SZ_FLG   = 8 * 32 * 32;                // uints
constexpr size_t WS_FLOATS = OFF_FLG + SZ_FLG;

// ---------------- prep: transpose + interleave weights, zero flags ----------------
__global__ __launch_bounds__(256) void prep_weights(
    const float* __restrict__ Wf, const float* __restrict__ Wi,
    const float* __restrict__ Wc, const float* __restrict__ Wo,
    const float* __restrict__ bf, const float* __restrict__ bi,
    const float* __restrict__ bc, const float* __restrict__ bo,
    float* __restrict__ ws)
{
    float* WT4 = ws + OFF_WT4;
    float* bI  = ws + OFF_BI;
    int idx = blockIdx.x * 256 + threadIdx.x;            // 65536 threads
    const float* Ws[4] = {Wf, Wi, Wc, Wo};
    #pragma unroll
    for (int j = 0; j < 6; ++j) {
        int item = idx + j * 65536;                      // [0, 393216)
        int k4   = item >> 11;                           // /2048
        int row  = item & 2047;
        int unit = row >> 2, gate = row & 3;
        const float* W = Ws[gate];
        float4 v = *(const float4*)(W + (size_t)unit * K + (size_t)k4 * 4);
        *(float4*)(WT4 + ((size_t)k4 * ROWS + row) * 4) = v;
    }
    if (idx < ROWS) {
        int unit = idx >> 2, gate = idx & 3;
        const float* bs[4] = {bf, bi, bc, bo};
        bI[idx] = bs[gate][unit];
    }
    if (idx < (int)SZ_FLG)
        ((unsigned int*)(ws + OFF_FLG))[idx] = 0u;
}

// ---------------- persistent LSTM kernel ----------------
// grid 256 = 32 row-groups x 8 seq-groups; bid = rg*8 + sg.
// block 256 thr = 4 waves; lane l owns row rg*64+l.
// Wave w k-slices: E cols [w*64, w*64+64), H cols [w*128, w*128+128).
//
// Cross-block protocol (NO fences anywhere in the loop — R4 showed agent acq_rel
// fences cost buffer_wbl2/inv per step = 218 KB/step forced HBM writes):
//  * h written/read ONLY via relaxed agent-scope atomics (sc0 sc1 -> coherent at LLC,
//    bypass the non-coherent XCD L2s; no dirty L2 lines -> nothing to flush).
//  * ordering: __syncthreads() drains vmcnt(0) per wave (compiler-guaranteed) before
//    tid0 posts its per-block flag; consumers poll flags (relaxed) then issue h loads
//    strictly after the poll branch -> in-order issue makes this HW-safe.
//  * dbuf WAR safety: a block reaches its h_{t+1} store (into hbuf[t&1]) only after
//    ALL its waves polled (union = all 32 flags >= t+1) and joined at a syncthreads,
//    i.e. after every block finished staging h_{t-1} out of hbuf[t&1].
__global__ __launch_bounds__(256, 1) void lstm_persist(
    float* __restrict__ ws,
    const int* __restrict__ x, const int* __restrict__ mask,
    const float* __restrict__ embed)
{
    __shared__ float emb_lds[2][8 * E];                  // 16 KB, dbuf (prefetch t+1)
    __shared__ float h_lds[8 * H];                       // 16 KB
    __shared__ float part_lds[4][8][64];                 // 8 KB

    const int bid = blockIdx.x;
    const int rg  = bid >> 3, sg = bid & 7;
    const int tid = threadIdx.x;
    const int w   = tid >> 6, l = tid & 63;
    const int seq_base = sg * 8;
    const int row = rg * 64 + l;
    const int gate = l & 3, qlane = l >> 2;

    const float4* WT4 = (const float4*)(ws + OFF_WT4);
    const float*  bI  = ws + OFF_BI;
    float* hbuf = ws + OFF_HB;
    float* repg = ws + OFF_REP;
    unsigned int* flg = (unsigned int*)(ws + OFF_FLG) + (size_t)sg * 32 * 32;

    // ---- stationary weights (E-slice and H-slice separated for overlap)
    float4 we[16], wh[32];
    #pragma unroll
    for (int j = 0; j < 16; ++j)
        we[j] = WT4[(size_t)(w * 16 + j) * ROWS + row];
    #pragma unroll
    for (int j = 0; j < 32; ++j)
        wh[j] = WT4[(size_t)(64 + w * 32 + j) * ROWS + row];
    const float breg = bI[row];

    // ---- per-owner-lane state (gate==0 lanes), 2 phases: seqs w and w+4
    float c0 = 0.f, c1 = 0.f, h0 = 0.f, h1 = 0.f, r0 = 0.f, r1 = 0.f;

    const int sl = tid >> 5, col = (tid & 31) * 8;       // emb gather mapping

    // ---- prologue: local emb gather for t=0, h_lds = 0
    {
        int tok = x[(size_t)(seq_base + sl) * L + 0];
        const float* er = embed + (size_t)tok * E + col;
        *(float4*)&emb_lds[0][sl * E + col]     = *(const float4*)er;
        *(float4*)&emb_lds[0][sl * E + col + 4] = *(const float4*)(er + 4);
        #pragma unroll
        for (int i = 0; i < 16; ++i) h_lds[tid + i * 256] = 0.f;
    }
    __syncthreads();

    for (int t = 0; t < L; ++t) {
        const int cur = t & 1, nxt = cur ^ 1;

        // (a) issue emb prefetch for t+1 (plain cached loads, read-only data)
        float4 e0, e1;
        const bool pf = (t + 1) < L;
        if (pf) {
            int tok = x[(size_t)(seq_base + sl) * L + (t + 1)];
            const float* er = embed + (size_t)tok * E + col;
            e0 = *(const float4*)er;
            e1 = *(const float4*)(er + 4);
        }

        // (b) wait for the 8 producers of THIS wave's h columns, then issue h loads
        float tmp[16];
        if (t > 0) {
            const unsigned int want = (unsigned int)t;
            int guard = 0;
            for (;;) {
                unsigned int v = (l < 8)
                    ? __hip_atomic_load(&flg[(size_t)(w * 8 + l) * 32],
                                        __ATOMIC_RELAXED, __HIP_MEMORY_SCOPE_AGENT)
                    : want;
                if (__all(v >= want) || ++guard > (1 << 17)) break;
                __builtin_amdgcn_s_sleep(1);
            }
            asm volatile("" ::: "memory");               // no compiler reorder across poll
            // wave w stages h cols [w*128, w*128+128) for 8 seqs (coherent loads, 16/thread)
            float* hs = hbuf + (size_t)cur * B * H + (size_t)seq_base * H;
            #pragma unroll
            for (int i = 0; i < 16; ++i) {
                int seq = i >> 1, coff = (i & 1) * 64 + l;
                tmp[i] = __hip_atomic_load(&hs[(size_t)seq * H + w * 128 + coff],
                                           __ATOMIC_RELAXED, __HIP_MEMORY_SCOPE_AGENT);
            }
        }

        // (c) GEMV E-part while h loads are in flight (uses emb_lds[cur], no h dep)
        float acc[8] = {0.f, 0.f, 0.f, 0.f, 0.f, 0.f, 0.f, 0.f};
        const float* eb = &emb_lds[cur][0] + w * 64;
        #pragma unroll
        for (int j = 0; j < 16; ++j) {
            float4 wv = we[j];
            #pragma unroll
            for (int s8 = 0; s8 < 8; ++s8) {
                float4 c4 = *(const float4*)(eb + s8 * E + j * 4);  // wave-uniform broadcast
                acc[s8] = fmaf(wv.x, c4.x, acc[s8]);
                acc[s8] = fmaf(wv.y, c4.y, acc[s8]);
                acc[s8] = fmaf(wv.z, c4.z, acc[s8]);
                acc[s8] = fmaf(wv.w, c4.w, acc[s8]);
            }
        }

        // (d) land prefetched emb and staged h into LDS
        if (pf) {
            *(float4*)&emb_lds[nxt][sl * E + col]     = e0;
            *(float4*)&emb_lds[nxt][sl * E + col + 4] = e1;
        }
        if (t > 0) {
            #pragma unroll
            for (int i = 0; i < 16; ++i) {
                int seq = i >> 1, coff = (i & 1) * 64 + l;
                h_lds[seq * H + w * 128 + coff] = tmp[i];
            }
        }
        __syncthreads();                                 // S1: h_lds/emb ready, all waves polled

        // (e) GEMV H-part
        const float* hb2 = &h_lds[0] + w * 128;
        #pragma unroll
        for (int j = 0; j < 32; ++j) {
            float4 wv = wh[j];
            #pragma unroll
            for (int s8 = 0; s8 < 8; ++s8) {
                float4 c4 = *(const float4*)(hb2 + s8 * H + j * 4); // wave-uniform broadcast
                acc[s8] = fmaf(wv.x, c4.x, acc[s8]);
                acc[s8] = fmaf(wv.y, c4.y, acc[s8]);
                acc[s8] = fmaf(wv.z, c4.z, acc[s8]);
                acc[s8] = fmaf(wv.w, c4.w, acc[s8]);
            }
        }
        #pragma unroll
        for (int s8 = 0; s8 < 8; ++s8)
            part_lds[w][s8][l] = acc[s8];
        __syncthreads();                                 // S2

        // (f) reduce k-slices, activations, c/h update (2 phases: seq = p*4 + w)
        #pragma unroll
        for (int p = 0; p < 2; ++p) {
            int s8 = p * 4 + w;
            float a = part_lds[0][s8][l] + part_lds[1][s8][l]
                    + part_lds[2][s8][l] + part_lds[3][s8][l] + breg;
            float act = (gate == 2) ? tanhf(a) : 1.f / (1.f + expf(-a));
            int base = l & ~3;
            float fg = __shfl(act, base),     ig = __shfl(act, base + 1);
            float cg = __shfl(act, base + 2), og = __shfl(act, base + 3);
            if (gate == 0) {
                float& cr = p ? c1 : c0;
                float& hr = p ? h1 : h0;
                float& rr = p ? r1 : r0;
                cr = fg * cr + ig * cg;                  // c not mask-blended (matches ref)
                float hn = og * tanhf(cr);
                int seq = seq_base + s8;
                float m = (mask[(size_t)seq * L + t] != 0) ? 1.f : 0.f;
                float h = hn * m + hr * (1.f - m);
                hr = h;
                // coherent (sc0 sc1) store -> LLC, never dirties an XCD L2
                __hip_atomic_store(
                    &hbuf[(size_t)nxt * B * H + (size_t)seq * H + rg * 16 + qlane],
                    h, __ATOMIC_RELAXED, __HIP_MEMORY_SCOPE_AGENT);
                rr += h * m;
            }
        }
        __syncthreads();                                 // S3: per-wave vmcnt(0) drain -> all
                                                         // h stores at coherence point
        if (tid == 0 && t < L - 1) {
            asm volatile("s_waitcnt vmcnt(0)" ::: "memory");  // belt-and-suspenders
            __hip_atomic_store(&flg[(size_t)rg * 32], (unsigned int)(t + 1),
                               __ATOMIC_RELAXED, __HIP_MEMORY_SCOPE_AGENT);
        }
    }

    // ---- epilogue: dump rep registers (unique owner per (seq,unit))
    if (gate == 0) {
        repg[(size_t)(seq_base + w)     * H + rg * 16 + qlane] = r0;
        repg[(size_t)(seq_base + w + 4) * H + rg * 16 + qlane] = r1;
    }
}

// ---------------- final: rep mean + logits ----------------
__global__ __launch_bounds__(256) void lstm_final(
    const float* __restrict__ ws,
    const int* __restrict__ mask,
    const float* __restrict__ Wfc, const float* __restrict__ bfc,
    float* __restrict__ out)
{
    __shared__ float sred[256];
    __shared__ float srep[H];
    int s = blockIdx.x, tid = threadIdx.x;

    float dsum = 0.f;
    for (int i = tid; i < L; i += 256) dsum += (mask[(size_t)s * L + i] != 0) ? 1.f : 0.f;
    sred[tid] = dsum; __syncthreads();
    for (int off = 128; off > 0; off >>= 1) {
        if (tid < off) sred[tid] += sred[tid + off];
        __syncthreads();
    }
    float denom = fmaxf(sred[0], 1e-9f);
    __syncthreads();

    const float* repa = ws + OFF_REP + (size_t)s * H;
    for (int i = tid; i < H; i += 256) {
        float r = repa[i] / denom;
        srep[i] = r;
        out[128 + (size_t)s * H + i] = r;
    }
    __syncthreads();

    for (int c = 0; c < 2; ++c) {
        float d = 0.f;
        for (int i = tid; i < H; i += 256) d += srep[i] * Wfc[(size_t)c * H + i];
        sred[tid] = d; __syncthreads();
        for (int off = 128; off > 0; off >>= 1) {
            if (tid < off) sred[tid] += sred[tid + off];
            __syncthreads();
        }
        if (tid == 0) out[(size_t)s * 2 + c] = sred[0] + bfc[c];
        __syncthreads();
    }
}

// ---------------- host ----------------
extern "C" void kernel_launch(void* const* d_in, const int* in_sizes, int n_in,
                              void* d_out, int out_size, void* d_ws, size_t ws_size,
                              hipStream_t stream)
{
    const int*   x     = (const int*)d_in[0];
    const int*   mask  = (const int*)d_in[1];
    const float* embed = (const float*)d_in[2];
    const float* Wf = (const float*)d_in[3];  const float* bf = (const float*)d_in[4];
    const float* Wi = (const float*)d_in[5];  const float* bi = (const float*)d_in[6];
    const float* Wc = (const float*)d_in[7];  const float* bc = (const float*)d_in[8];
    const float* Wo = (const float*)d_in[9];  const float* bo = (const float*)d_in[10];
    const float* Wfc = (const float*)d_in[11]; const float* bfc = (const float*)d_in[12];
    float* out = (float*)d_out;
    float* ws  = (float*)d_ws;

    if (ws_size < WS_FLOATS * sizeof(float)) {
        return; // leave output poisoned so the failure mode is unambiguous
    }

    prep_weights<<<256, 256, 0, stream>>>(Wf, Wi, Wc, Wo, bf, bi, bc, bo, ws);
    lstm_persist<<<256, 256, 0, stream>>>(ws, x, mask, embed);
    lstm_final<<<64, 256, 0, stream>>>(ws, mask, Wfc, bfc, out);
}

// Round 2
// 10936.906 us; speedup vs baseline: 1.2424x; 1.2424x over previous
//
#include <hip/hip_runtime.h>

// ---------------- problem constants ----------------
constexpr int B = 64, L = 512, E = 256, H = 512;
constexpr int ROWS = 4 * H;      // 2048 gate-rows (unit*4 + gate interleave)
constexpr int K    = E + H;      // 768
constexpr int K4   = K / 4;      // 192

// ---------------- ws layout (in floats) ----------------
constexpr size_t OFF_WT4  = 0;
constexpr size_t SZ_WT4   = (size_t)K4 * ROWS * 4;      // float4[K4][ROWS]
constexpr size_t OFF_BI   = OFF_WT4 + SZ_WT4;           // interleaved biases [ROWS]
constexpr size_t SZ_BI    = ROWS;
constexpr size_t OFF_COMB = OFF_BI + SZ_BI;             // comb dbuf [2][B][K]
constexpr size_t SZ_COMB  = (size_t)2 * B * K;
constexpr size_t OFF_REP  = OFF_COMB + SZ_COMB;         // rep accumulator [B][H]
constexpr size_t SZ_REP   = (size_t)B * H;
constexpr size_t OFF_FLG  = OFF_REP + SZ_REP;           // flags [8 sg][32 rg], 128B apart
constexpr size_t SZ_FLG   = 8 * 32 * 32;                // uints
constexpr size_t WS_FLOATS = OFF_FLG + SZ_FLG;

// ---------------- prep: transpose + interleave weights, zero flags ----------------
__global__ __launch_bounds__(256) void prep_weights(
    const float* __restrict__ Wf, const float* __restrict__ Wi,
    const float* __restrict__ Wc, const float* __restrict__ Wo,
    const float* __restrict__ bf, const float* __restrict__ bi,
    const float* __restrict__ bc, const float* __restrict__ bo,
    float* __restrict__ ws)
{
    float* WT4 = ws + OFF_WT4;
    float* bI  = ws + OFF_BI;
    int idx = blockIdx.x * 256 + threadIdx.x;            // 65536 threads
    const float* Ws[4] = {Wf, Wi, Wc, Wo};
    #pragma unroll
    for (int j = 0; j < 6; ++j) {
        int item = idx + j * 65536;                      // [0, 393216)
        int k4   = item >> 11;                           // /2048
        int row  = item & 2047;
        int unit = row >> 2, gate = row & 3;
        const float* W = Ws[gate];
        float4 v = *(const float4*)(W + (size_t)unit * K + (size_t)k4 * 4);
        *(float4*)(WT4 + ((size_t)k4 * ROWS + row) * 4) = v;
    }
    if (idx < ROWS) {
        int unit = idx >> 2, gate = idx & 3;
        const float* bs[4] = {bf, bi, bc, bo};
        bI[idx] = bs[gate][unit];
    }
    if (idx < (int)SZ_FLG)
        ((unsigned int*)(ws + OFF_FLG))[idx] = 0u;
}

// ---------------- persistent LSTM kernel ----------------
// grid 256 = 32 row-groups x 8 seq-groups; bid = rg*8 + sg.
// block 256 thr = 4 waves; lane l owns row rg*64+l; wave w = k-slice w*192..
//
// REGISTER STRUCTURE IS ROUND-0's (do not split wreg / add live arrays!):
// single wreg[48] float4 -> compiler promotes to AGPRs (VGPR_Count 128).
// R5 split we/wh + tmp[16] -> promotion lost -> 25 GB/step.. scratch thrash.
//
// Cross-block protocol (fence-free; NO acq_rel anywhere in the loop):
//  * comb written/read ONLY via relaxed agent-scope atomics (sc1 -> coherent at
//    LLC, bypass non-coherent XCD L2s; nothing dirty in L2 -> no wbl2/inv cost).
//  * release: __syncthreads() drains vmcnt(0) per wave (compiler-guaranteed
//    before s_barrier) -> all stores at LLC before tid0 posts its flag.
//  * acquire: consumers poll 32 flags with 32 lanes (one load each), then issue
//    staging loads after the dependent branch -> in-order issue makes it safe.
//  * WAR on the dbuf: flag >= t+1 from block Q means Q finished step t-1 stores,
//    which (program order) means Q finished its step t-1 staging reads of
//    comb[(t+1)&1] -> safe to overwrite.
__global__ __launch_bounds__(256, 1) void lstm_persist(
    float* __restrict__ ws,
    const int* __restrict__ x, const int* __restrict__ mask,
    const float* __restrict__ embed)
{
    __shared__ float comb_lds[8 * K];                    // 24 KB
    __shared__ float part_lds[4][8][64];                 // 8 KB

    const int bid = blockIdx.x;
    const int rg  = bid >> 3, sg = bid & 7;
    const int tid = threadIdx.x;
    const int w   = tid >> 6, l = tid & 63;
    const int seq_base = sg * 8;
    const int row = rg * 64 + l;
    const int gate = l & 3, qlane = l >> 2;

    const float4* WT4 = (const float4*)(ws + OFF_WT4);
    const float*  bI  = ws + OFF_BI;
    float* combg = ws + OFF_COMB;
    float* repg  = ws + OFF_REP;
    unsigned int* flg = (unsigned int*)(ws + OFF_FLG) + (size_t)sg * 32 * 32;

    // ---- load stationary weights into registers (coalesced dwordx4)
    float4 wreg[48];
    #pragma unroll
    for (int j = 0; j < 48; ++j)
        wreg[j] = WT4[(size_t)(w * 48 + j) * ROWS + row];
    const float breg = bI[row];

    // ---- per-owner-lane state (lanes with gate==0), 2 phases: seqs w and w+4
    float c0 = 0.f, c1 = 0.f, h0 = 0.f, h1 = 0.f, r0 = 0.f, r1 = 0.f;

    const int sl = tid >> 5, col = (tid & 31) * 8;       // emb gather mapping

    // ---- prologue: comb[0] = [emb(t=0) | h=0], all through coherent stores
    if (gate == 0) {
        __hip_atomic_store(&combg[(size_t)(seq_base + w)     * K + E + rg * 16 + qlane],
                           0.f, __ATOMIC_RELAXED, __HIP_MEMORY_SCOPE_AGENT);
        __hip_atomic_store(&combg[(size_t)(seq_base + w + 4) * K + E + rg * 16 + qlane],
                           0.f, __ATOMIC_RELAXED, __HIP_MEMORY_SCOPE_AGENT);
    }
    if (rg == 0) {
        int tok = x[(size_t)(seq_base + sl) * L + 0];
        const float* er = embed + (size_t)tok * E + col;
        float4 a = *(const float4*)er, b = *(const float4*)(er + 4);
        float* dst = combg + (size_t)(seq_base + sl) * K + col;
        #pragma unroll
        for (int j = 0; j < 4; ++j) {
            __hip_atomic_store(&dst[j],     ((const float*)&a)[j],
                               __ATOMIC_RELAXED, __HIP_MEMORY_SCOPE_AGENT);
            __hip_atomic_store(&dst[4 + j], ((const float*)&b)[j],
                               __ATOMIC_RELAXED, __HIP_MEMORY_SCOPE_AGENT);
        }
    }
    __syncthreads();                                     // drains vmcnt(0) per wave
    if (tid == 0) {
        __hip_atomic_store(&flg[(size_t)rg * 32], 1u,
                           __ATOMIC_RELAXED, __HIP_MEMORY_SCOPE_AGENT);
    }

    // ---- main recurrence
    for (int t = 0; t < L; ++t) {
        const float* comb_c = combg + (size_t)(t & 1) * B * K + (size_t)seq_base * K;
        float*       comb_n = combg + (size_t)((t + 1) & 1) * B * K + (size_t)seq_base * K;

        // (a) issue emb loads for t+1 early (read-only, independent of flags)
        float4 e0, e1;
        const bool pf = (rg == 0) && ((t + 1) < L);
        if (pf) {
            int tok = x[(size_t)(seq_base + sl) * L + (t + 1)];
            const float* er = embed + (size_t)tok * E + col;
            e0 = *(const float4*)er;
            e1 = *(const float4*)(er + 4);
        }

        // (b) poll all 32 producer flags (lanes 0..31, all waves independently)
        {
            const unsigned int want = (unsigned int)(t + 1);
            int guard = 0;
            for (;;) {
                unsigned int v = (l < 32)
                    ? __hip_atomic_load(&flg[(size_t)l * 32],
                                        __ATOMIC_RELAXED, __HIP_MEMORY_SCOPE_AGENT)
                    : want;
                if (__all(v >= want) || ++guard > (1 << 17)) break;
                __builtin_amdgcn_s_sleep(1);
            }
            asm volatile("" ::: "memory");               // no reorder across poll
        }

        // (c) stage comb[8 seqs][K] into LDS via coherent scalar loads (coalesced)
        #pragma unroll
        for (int i = 0; i < 24; ++i) {
            int idx = tid + i * 256;                     // float idx 0..6143
            comb_lds[idx] = __hip_atomic_load(&comb_c[idx],
                                              __ATOMIC_RELAXED, __HIP_MEMORY_SCOPE_AGENT);
        }

        // (d) rg0: land pre-gathered emb for t+1 into comb_n (coherent stores)
        if (pf) {
            float* dst = comb_n + (size_t)sl * K + col;
            #pragma unroll
            for (int j = 0; j < 4; ++j) {
                __hip_atomic_store(&dst[j],     ((const float*)&e0)[j],
                                   __ATOMIC_RELAXED, __HIP_MEMORY_SCOPE_AGENT);
                __hip_atomic_store(&dst[4 + j], ((const float*)&e1)[j],
                                   __ATOMIC_RELAXED, __HIP_MEMORY_SCOPE_AGENT);
            }
        }
        __syncthreads();                                 // S1: comb_lds ready

        // (e) GEMV: j-outer / s8-inner, 8 independent accumulator chains
        float acc[8] = {0.f, 0.f, 0.f, 0.f, 0.f, 0.f, 0.f, 0.f};
        const float* clbase = comb_lds + w * 192;
        #pragma unroll
        for (int j = 0; j < 48; ++j) {
            float4 wv = wreg[j];
            #pragma unroll
            for (int s8 = 0; s8 < 8; ++s8) {
                float4 c4 = *(const float4*)(clbase + s8 * K + j * 4); // wave-uniform broadcast
                acc[s8] = fmaf(wv.x, c4.x, acc[s8]);
                acc[s8] = fmaf(wv.y, c4.y, acc[s8]);
                acc[s8] = fmaf(wv.z, c4.z, acc[s8]);
                acc[s8] = fmaf(wv.w, c4.w, acc[s8]);
            }
        }
        #pragma unroll
        for (int s8 = 0; s8 < 8; ++s8)
            part_lds[w][s8][l] = acc[s8];
        __syncthreads();                                 // S2

        // (f) reduce k-slices, activations, c/h update (2 phases: seq = p*4 + w)
        #pragma unroll
        for (int p = 0; p < 2; ++p) {
            int s8 = p * 4 + w;
            float a = part_lds[0][s8][l] + part_lds[1][s8][l]
                    + part_lds[2][s8][l] + part_lds[3][s8][l] + breg;
            float act = (gate == 2) ? tanhf(a) : 1.f / (1.f + expf(-a));
            int base = l & ~3;
            float fg = __shfl(act, base),     ig = __shfl(act, base + 1);
            float cg = __shfl(act, base + 2), og = __shfl(act, base + 3);
            if (gate == 0) {
                float& cr = p ? c1 : c0;
                float& hr = p ? h1 : h0;
                float& rr = p ? r1 : r0;
                cr = fg * cr + ig * cg;                  // c not mask-blended (matches ref)
                float hn = og * tanhf(cr);
                int seq = seq_base + s8;
                float m = (mask[(size_t)seq * L + t] != 0) ? 1.f : 0.f;
                float h = hn * m + hr * (1.f - m);
                hr = h;
                __hip_atomic_store(&comb_n[(size_t)s8 * K + E + rg * 16 + qlane],
                                   h, __ATOMIC_RELAXED, __HIP_MEMORY_SCOPE_AGENT);
                rr += h * m;
            }
        }
        __syncthreads();                                 // S3: vmcnt(0) drain per wave ->
                                                         // all h (and rg0 emb) stores at LLC
        if (tid == 0 && t < L - 1) {
            asm volatile("s_waitcnt vmcnt(0)" ::: "memory");  // belt-and-suspenders
            __hip_atomic_store(&flg[(size_t)rg * 32], (unsigned int)(t + 2),
                               __ATOMIC_RELAXED, __HIP_MEMORY_SCOPE_AGENT);
        }
    }

    // ---- epilogue: dump rep registers (unique owner per (seq,unit))
    if (gate == 0) {
        repg[(size_t)(seq_base + w)     * H + rg * 16 + qlane] = r0;
        repg[(size_t)(seq_base + w + 4) * H + rg * 16 + qlane] = r1;
    }
}

// ---------------- final: rep mean + logits ----------------
__global__ __launch_bounds__(256) void lstm_final(
    const float* __restrict__ ws,
    const int* __restrict__ mask,
    const float* __restrict__ Wfc, const float* __restrict__ bfc,
    float* __restrict__ out)
{
    __shared__ float sred[256];
    __shared__ float srep[H];
    int s = blockIdx.x, tid = threadIdx.x;

    float dsum = 0.f;
    for (int i = tid; i < L; i += 256) dsum += (mask[(size_t)s * L + i] != 0) ? 1.f : 0.f;
    sred[tid] = dsum; __syncthreads();
    for (int off = 128; off > 0; off >>= 1) {
        if (tid < off) sred[tid] += sred[tid + off];
        __syncthreads();
    }
    float denom = fmaxf(sred[0], 1e-9f);
    __syncthreads();

    const float* repa = ws + OFF_REP + (size_t)s * H;
    for (int i = tid; i < H; i += 256) {
        float r = repa[i] / denom;
        srep[i] = r;
        out[128 + (size_t)s * H + i] = r;
    }
    __syncthreads();

    for (int c = 0; c < 2; ++c) {
        float d = 0.f;
        for (int i = tid; i < H; i += 256) d += srep[i] * Wfc[(size_t)c * H + i];
        sred[tid] = d; __syncthreads();
        for (int off = 128; off > 0; off >>= 1) {
            if (tid < off) sred[tid] += sred[tid + off];
            __syncthreads();
        }
        if (tid == 0) out[(size_t)s * 2 + c] = sred[0] + bfc[c];
        __syncthreads();
    }
}

// ---------------- host ----------------
extern "C" void kernel_launch(void* const* d_in, const int* in_sizes, int n_in,
                              void* d_out, int out_size, void* d_ws, size_t ws_size,
                              hipStream_t stream)
{
    const int*   x     = (const int*)d_in[0];
    const int*   mask  = (const int*)d_in[1];
    const float* embed = (const float*)d_in[2];
    const float* Wf = (const float*)d_in[3];  const float* bf = (const float*)d_in[4];
    const float* Wi = (const float*)d_in[5];  const float* bi = (const float*)d_in[6];
    const float* Wc = (const float*)d_in[7];  const float* bc = (const float*)d_in[8];
    const float* Wo = (const float*)d_in[9];  const float* bo = (const float*)d_in[10];
    const float* Wfc = (const float*)d_in[11]; const float* bfc = (const float*)d_in[12];
    float* out = (float*)d_out;
    float* ws  = (float*)d_ws;

    if (ws_size < WS_FLOATS * sizeof(float)) {
        return; // leave output poisoned so the failure mode is unambiguous
    }

    prep_weights<<<256, 256, 0, stream>>>(Wf, Wi, Wc, Wo, bf, bi, bc, bo, ws);
    lstm_persist<<<256, 256, 0, stream>>>(ws, x, mask, embed);
    lstm_final<<<64, 256, 0, stream>>>(ws, mask, Wfc, bfc, out);
}

// Round 3
// 10623.519 us; speedup vs baseline: 1.2790x; 1.0295x over previous
//
#include <hip/hip_runtime.h>

// ---------------- problem constants ----------------
constexpr int B = 64, L = 512, E = 256, H = 512;
constexpr int ROWS = 4 * H;      // 2048 gate-rows (unit*4 + gate interleave)
constexpr int K    = E + H;      // 768
constexpr int K4   = K / 4;      // 192

// ---------------- ws layout (in floats) ----------------
constexpr size_t OFF_WT4   = 0;
constexpr size_t SZ_WT4    = (size_t)K4 * ROWS * 4;     // float4[K4][ROWS]
constexpr size_t OFF_BI    = OFF_WT4 + SZ_WT4;          // interleaved biases [ROWS]
constexpr size_t SZ_BI     = ROWS;
constexpr size_t OFF_COMB2 = OFF_BI + SZ_BI;            // TAGGED comb dbuf [2][B][K] x (val,tag)
constexpr size_t SZ_COMB2  = (size_t)2 * B * K * 2;     // in floats (u64 per element)
constexpr size_t OFF_REP   = OFF_COMB2 + SZ_COMB2;      // rep accumulator [B][H]
constexpr size_t SZ_REP    = (size_t)B * H;
constexpr size_t WS_FLOATS = OFF_REP + SZ_REP;

// ---------------- prep: transpose + interleave weights, invalidate comb tags ----------------
__global__ __launch_bounds__(256) void prep_weights(
    const float* __restrict__ Wf, const float* __restrict__ Wi,
    const float* __restrict__ Wc, const float* __restrict__ Wo,
    const float* __restrict__ bf, const float* __restrict__ bi,
    const float* __restrict__ bc, const float* __restrict__ bo,
    float* __restrict__ ws)
{
    float* WT4 = ws + OFF_WT4;
    float* bI  = ws + OFF_BI;
    int idx = blockIdx.x * 256 + threadIdx.x;            // 65536 threads
    const float* Ws[4] = {Wf, Wi, Wc, Wo};
    #pragma unroll
    for (int j = 0; j < 6; ++j) {
        int item = idx + j * 65536;                      // [0, 393216)
        int k4   = item >> 11;                           // /2048
        int row  = item & 2047;
        int unit = row >> 2, gate = row & 3;
        const float* W = Ws[gate];
        float4 v = *(const float4*)(W + (size_t)unit * K + (size_t)k4 * 4);
        *(float4*)(WT4 + ((size_t)k4 * ROWS + row) * 4) = v;
    }
    if (idx < ROWS) {
        int unit = idx >> 2, gate = idx & 3;
        const float* bs[4] = {bf, bi, bc, bo};
        bI[idx] = bs[gate][unit];
    }
    // zero all tags (tag 0 matches no want >= 1); plain stores are safe:
    // end-of-dispatch L2 writeback makes them visible to persist's sc-bypass loads
    // (validated in R2: prep's plain flag zeroing was read via agent-scope loads).
    unsigned long long* c2 = (unsigned long long*)(ws + OFF_COMB2);
    #pragma unroll
    for (int j = 0; j < 6; ++j)                          // 6*65536 = 2*B*K u64s exactly
        c2[(size_t)idx + (size_t)j * 65536] = 0ull;
}

// ---------------- persistent LSTM kernel ----------------
// grid 256 = 32 row-groups x 8 seq-groups; bid = rg*8 + sg.
// block 256 thr = 4 waves; lane l owns row rg*64+l; wave w = k-slice w*192..
//
// REGISTER STRUCTURE IS ROUND-0/2's (do not split wreg / add big live arrays):
// single wreg[48] float4 -> compiler promotes to AGPRs (VGPR_Count ~132).
// R1's split we/wh -> promotion lost -> 25 GB scratch thrash, 256 VGPR.
//
// Cross-block protocol (single-round-trip, fence-free, barrier-free release):
//  * every comb element is an 8-byte atomic (f32 value, u32 tag). Producers store
//    (v, t+2) with ONE relaxed agent-scope store: atomicity delivers value+tag
//    together, so no release ordering, no drain, no flag, no post-store barrier.
//  * consumers' staging loop IS the poll: load 24 tagged u64s (coalesced, sc-bypass
//    -> LLC), stash values in LDS, retry until __all(tags == t+1).
//  * WAR on the dbuf: the per-step all-gather bounds skew between blocks of a chain
//    to < 1 iteration, so tag-t data in slot t&1 is consumed by everyone before any
//    producer (which must first gather ALL tag-t+1 data) can overwrite with t+2.
//    Same induction as R2's flag argument; tags make staleness directly visible.
__global__ __launch_bounds__(256, 1) void lstm_persist(
    float* __restrict__ ws,
    const int* __restrict__ x, const int* __restrict__ mask,
    const float* __restrict__ embed)
{
    __shared__ float comb_lds[8 * K];                    // 24 KB
    __shared__ float part_lds[4][8][64];                 // 8 KB

    const int bid = blockIdx.x;
    const int rg  = bid >> 3, sg = bid & 7;
    const int tid = threadIdx.x;
    const int w   = tid >> 6, l = tid & 63;
    const int seq_base = sg * 8;
    const int row = rg * 64 + l;
    const int gate = l & 3, qlane = l >> 2;

    const float4* WT4 = (const float4*)(ws + OFF_WT4);
    const float*  bI  = ws + OFF_BI;
    unsigned long long* comb2 = (unsigned long long*)(ws + OFF_COMB2);
    float* repg = ws + OFF_REP;

    // ---- load stationary weights into registers (coalesced dwordx4)
    float4 wreg[48];
    #pragma unroll
    for (int j = 0; j < 48; ++j)
        wreg[j] = WT4[(size_t)(w * 48 + j) * ROWS + row];
    const float breg = bI[row];

    // ---- per-owner-lane state (lanes with gate==0), 2 phases: seqs w and w+4
    float c0 = 0.f, c1 = 0.f, h0 = 0.f, h1 = 0.f, r0 = 0.f, r1 = 0.f;

    const int sl = tid >> 5, col = (tid & 31) * 8;       // emb gather mapping

    // ---- prologue: slot0 = [emb(t=0) | h=0], everything tagged 1; no barrier needed,
    //      the first staging poll synchronizes.
    if (gate == 0) {
        unsigned long long z = ((unsigned long long)1u << 32); // (0.0f, tag 1)
        __hip_atomic_store(&comb2[(size_t)(seq_base + w)     * K + E + rg * 16 + qlane],
                           z, __ATOMIC_RELAXED, __HIP_MEMORY_SCOPE_AGENT);
        __hip_atomic_store(&comb2[(size_t)(seq_base + w + 4) * K + E + rg * 16 + qlane],
                           z, __ATOMIC_RELAXED, __HIP_MEMORY_SCOPE_AGENT);
    }
    if (rg == 0) {
        int tok = x[(size_t)(seq_base + sl) * L + 0];
        const float* er = embed + (size_t)tok * E + col;
        float4 a = *(const float4*)er, b = *(const float4*)(er + 4);
        unsigned long long* dst = comb2 + (size_t)(seq_base + sl) * K + col;
        #pragma unroll
        for (int j = 0; j < 8; ++j) {
            float v = (j < 4) ? ((const float*)&a)[j] : ((const float*)&b)[j - 4];
            unsigned long long p = ((unsigned long long)1u << 32)
                                 | (unsigned long long)__float_as_uint(v);
            __hip_atomic_store(&dst[j], p, __ATOMIC_RELAXED, __HIP_MEMORY_SCOPE_AGENT);
        }
    }

    // ---- main recurrence: 2 barriers per step, zero flags, zero fences
    for (int t = 0; t < L; ++t) {
        const unsigned long long* c2c = comb2 + (size_t)(t & 1) * B * K
                                              + (size_t)seq_base * K;
        unsigned long long*       c2n = comb2 + (size_t)((t + 1) & 1) * B * K
                                              + (size_t)seq_base * K;

        // (a) issue emb loads for t+1 early (read-only, independent of sync)
        float4 e0, e1;
        const bool pf = (rg == 0) && ((t + 1) < L);
        if (pf) {
            int tok = x[(size_t)(seq_base + sl) * L + (t + 1)];
            const float* er = embed + (size_t)tok * E + col;
            e0 = *(const float4*)er;
            e1 = *(const float4*)(er + 4);
        }

        // (b) tagged staging-poll: one LLC round trip per attempt
        {
            const unsigned int want = (unsigned int)(t + 1);
            int guard = 0;
            for (;;) {
                bool ok = true;
                #pragma unroll
                for (int i = 0; i < 24; ++i) {
                    int idx = tid + i * 256;             // u64 idx 0..6143
                    unsigned long long v = __hip_atomic_load(
                        &c2c[idx], __ATOMIC_RELAXED, __HIP_MEMORY_SCOPE_AGENT);
                    comb_lds[idx] = __uint_as_float((unsigned int)v);
                    ok &= ((unsigned int)(v >> 32) == want);
                }
                if (__all(ok) || ++guard > (1 << 20)) break;
                __builtin_amdgcn_s_sleep(2);
            }
        }

        // (c) rg0: land pre-gathered emb for t+1 (tagged t+2, single atomic each)
        if (pf) {
            unsigned long long* dst = c2n + (size_t)sl * K + col;
            const unsigned long long hi = ((unsigned long long)(unsigned int)(t + 2)) << 32;
            #pragma unroll
            for (int j = 0; j < 8; ++j) {
                float v = (j < 4) ? ((const float*)&e0)[j] : ((const float*)&e1)[j - 4];
                __hip_atomic_store(&dst[j], hi | (unsigned long long)__float_as_uint(v),
                                   __ATOMIC_RELAXED, __HIP_MEMORY_SCOPE_AGENT);
            }
        }
        __syncthreads();                                 // S1: comb_lds ready

        // (d) GEMV: j-outer / s8-inner, 8 independent accumulator chains
        float acc[8] = {0.f, 0.f, 0.f, 0.f, 0.f, 0.f, 0.f, 0.f};
        const float* clbase = comb_lds + w * 192;
        #pragma unroll
        for (int j = 0; j < 48; ++j) {
            float4 wv = wreg[j];
            #pragma unroll
            for (int s8 = 0; s8 < 8; ++s8) {
                float4 c4 = *(const float4*)(clbase + s8 * K + j * 4); // wave-uniform broadcast
                acc[s8] = fmaf(wv.x, c4.x, acc[s8]);
                acc[s8] = fmaf(wv.y, c4.y, acc[s8]);
                acc[s8] = fmaf(wv.z, c4.z, acc[s8]);
                acc[s8] = fmaf(wv.w, c4.w, acc[s8]);
            }
        }
        #pragma unroll
        for (int s8 = 0; s8 < 8; ++s8)
            part_lds[w][s8][l] = acc[s8];
        __syncthreads();                                 // S2

        // (e) reduce k-slices, activations, c/h update (2 phases: seq = p*4 + w)
        #pragma unroll
        for (int p = 0; p < 2; ++p) {
            int s8 = p * 4 + w;
            float a = part_lds[0][s8][l] + part_lds[1][s8][l]
                    + part_lds[2][s8][l] + part_lds[3][s8][l] + breg;
            float act = (gate == 2) ? tanhf(a) : 1.f / (1.f + expf(-a));
            int base = l & ~3;
            float fg = __shfl(act, base),     ig = __shfl(act, base + 1);
            float cg = __shfl(act, base + 2), og = __shfl(act, base + 3);
            if (gate == 0) {
                float& cr = p ? c1 : c0;
                float& hr = p ? h1 : h0;
                float& rr = p ? r1 : r0;
                cr = fg * cr + ig * cg;                  // c not mask-blended (matches ref)
                float hn = og * tanhf(cr);
                int seq = seq_base + s8;
                float m = (mask[(size_t)seq * L + t] != 0) ? 1.f : 0.f;
                float h = hn * m + hr * (1.f - m);
                hr = h;
                // single 8B atomic carries value AND readiness -> no release needed
                unsigned long long p64 = (((unsigned long long)(unsigned int)(t + 2)) << 32)
                                       | (unsigned long long)__float_as_uint(h);
                __hip_atomic_store(&c2n[(size_t)s8 * K + E + rg * 16 + qlane],
                                   p64, __ATOMIC_RELAXED, __HIP_MEMORY_SCOPE_AGENT);
                rr += h * m;
            }
        }
        // NO S3, NO flag store: next iteration's poll is the only consumer-side gate.
    }

    // ---- epilogue: dump rep registers (unique owner per (seq,unit))
    if (gate == 0) {
        repg[(size_t)(seq_base + w)     * H + rg * 16 + qlane] = r0;
        repg[(size_t)(seq_base + w + 4) * H + rg * 16 + qlane] = r1;
    }
}

// ---------------- final: rep mean + logits ----------------
__global__ __launch_bounds__(256) void lstm_final(
    const float* __restrict__ ws,
    const int* __restrict__ mask,
    const float* __restrict__ Wfc, const float* __restrict__ bfc,
    float* __restrict__ out)
{
    __shared__ float sred[256];
    __shared__ float srep[H];
    int s = blockIdx.x, tid = threadIdx.x;

    float dsum = 0.f;
    for (int i = tid; i < L; i += 256) dsum += (mask[(size_t)s * L + i] != 0) ? 1.f : 0.f;
    sred[tid] = dsum; __syncthreads();
    for (int off = 128; off > 0; off >>= 1) {
        if (tid < off) sred[tid] += sred[tid + off];
        __syncthreads();
    }
    float denom = fmaxf(sred[0], 1e-9f);
    __syncthreads();

    const float* repa = ws + OFF_REP + (size_t)s * H;
    for (int i = tid; i < H; i += 256) {
        float r = repa[i] / denom;
        srep[i] = r;
        out[128 + (size_t)s * H + i] = r;
    }
    __syncthreads();

    for (int c = 0; c < 2; ++c) {
        float d = 0.f;
        for (int i = tid; i < H; i += 256) d += srep[i] * Wfc[(size_t)c * H + i];
        sred[tid] = d; __syncthreads();
        for (int off = 128; off > 0; off >>= 1) {
            if (tid < off) sred[tid] += sred[tid + off];
            __syncthreads();
        }
        if (tid == 0) out[(size_t)s * 2 + c] = sred[0] + bfc[c];
        __syncthreads();
    }
}

// ---------------- host ----------------
extern "C" void kernel_launch(void* const* d_in, const int* in_sizes, int n_in,
                              void* d_out, int out_size, void* d_ws, size_t ws_size,
                              hipStream_t stream)
{
    const int*   x     = (const int*)d_in[0];
    const int*   mask  = (const int*)d_in[1];
    const float* embed = (const float*)d_in[2];
    const float* Wf = (const float*)d_in[3];  const float* bf = (const float*)d_in[4];
    const float* Wi = (const float*)d_in[5];  const float* bi = (const float*)d_in[6];
    const float* Wc = (const float*)d_in[7];  const float* bc = (const float*)d_in[8];
    const float* Wo = (const float*)d_in[9];  const float* bo = (const float*)d_in[10];
    const float* Wfc = (const float*)d_in[11]; const float* bfc = (const float*)d_in[12];
    float* out = (float*)d_out;
    float* ws  = (float*)d_ws;

    if (ws_size < WS_FLOATS * sizeof(float)) {
        return; // leave output poisoned so the failure mode is unambiguous
    }

    prep_weights<<<256, 256, 0, stream>>>(Wf, Wi, Wc, Wo, bf, bi, bc, bo, ws);
    lstm_persist<<<256, 256, 0, stream>>>(ws, x, mask, embed);
    lstm_final<<<64, 256, 0, stream>>>(ws, mask, Wfc, bfc, out);
}

// Round 4
// 4534.294 us; speedup vs baseline: 2.9966x; 2.3429x over previous
//
#include <hip/hip_runtime.h>

// ---------------- problem constants ----------------
constexpr int B = 64, L = 512, E = 256, H = 512;
constexpr int ROWS = 4 * H;      // 2048 gate-rows (unit*4 + gate interleave)
constexpr int K    = E + H;      // 768
constexpr int K4   = K / 4;      // 192

// ---------------- ws layout (in floats) ----------------
constexpr size_t OFF_WT4   = 0;
constexpr size_t SZ_WT4    = (size_t)K4 * ROWS * 4;     // float4[K4][ROWS]
constexpr size_t OFF_BI    = OFF_WT4 + SZ_WT4;          // interleaved biases [ROWS]
constexpr size_t SZ_BI     = ROWS;
constexpr size_t OFF_COMB2 = OFF_BI + SZ_BI;            // TAGGED comb dbuf [2][B][K] x (val,tag)
constexpr size_t SZ_COMB2  = (size_t)2 * B * K * 2;     // in floats (u64 per element)
constexpr size_t OFF_REP   = OFF_COMB2 + SZ_COMB2;      // rep accumulator [B][H]
constexpr size_t SZ_REP    = (size_t)B * H;
constexpr size_t WS_FLOATS = OFF_REP + SZ_REP;

// ---------------- prep: transpose + interleave weights, invalidate comb tags ----------------
__global__ __launch_bounds__(256) void prep_weights(
    const float* __restrict__ Wf, const float* __restrict__ Wi,
    const float* __restrict__ Wc, const float* __restrict__ Wo,
    const float* __restrict__ bf, const float* __restrict__ bi,
    const float* __restrict__ bc, const float* __restrict__ bo,
    float* __restrict__ ws)
{
    float* WT4 = ws + OFF_WT4;
    float* bI  = ws + OFF_BI;
    int idx = blockIdx.x * 256 + threadIdx.x;            // 65536 threads
    const float* Ws[4] = {Wf, Wi, Wc, Wo};
    #pragma unroll
    for (int j = 0; j < 6; ++j) {
        int item = idx + j * 65536;                      // [0, 393216)
        int k4   = item >> 11;                           // /2048
        int row  = item & 2047;
        int unit = row >> 2, gate = row & 3;
        const float* W = Ws[gate];
        float4 v = *(const float4*)(W + (size_t)unit * K + (size_t)k4 * 4);
        *(float4*)(WT4 + ((size_t)k4 * ROWS + row) * 4) = v;
    }
    if (idx < ROWS) {
        int unit = idx >> 2, gate = idx & 3;
        const float* bs[4] = {bf, bi, bc, bo};
        bI[idx] = bs[gate][unit];
    }
    // zero all tags (tag 0 matches no want >= 1); end-of-dispatch L2 writeback makes
    // these visible to persist's sc-bypass loads (validated R2/R3).
    unsigned long long* c2 = (unsigned long long*)(ws + OFF_COMB2);
    #pragma unroll
    for (int j = 0; j < 6; ++j)                          // 6*65536 = 2*B*K u64s exactly
        c2[(size_t)idx + (size_t)j * 65536] = 0ull;
}

// ---------------- persistent LSTM kernel ----------------
// grid 256 = 32 row-groups x 8 seq-groups; bid = rg*8 + sg.
// block 256 thr = 4 waves.
//
// R4 RESTRUCTURE (LDS-issue theory): GEMV is 2 rows/lane x 24 k4 (was 1x48) so each
// wave-broadcast ds_read_b128 feeds 8 FMAs (was 4) -> GEMV LDS reads halved
// (384 -> 192 per wave per step). Quad shuffles moved to VALU mov_dpp (off LDS pipe).
// Staging LDS writes 24xb32 -> 12xb64. All 4 waves share ONE LDS pipe per CU and
// occupancy is 1 wave/SIMD, so LDS issue is the serialized resource.
//
// REGISTER RULE (R1 failure): keep weights in ONE wreg[48] float4 array, constant
// indices only -> compiler promotes to AGPRs. Splitting it spilled 25 GB to scratch.
//
// Cross-block protocol = R3's tagged scheme (correct, 1 LLC round trip):
//  * every comb element is an 8-byte atomic (f32 value, u32 tag); producers store
//    (v, t+2) with ONE relaxed agent-scope store (atomicity carries readiness).
//  * consumers' staging loop IS the poll: load tagged u64s, stash values in LDS,
//    retry until __all(tags == want).
//  * WAR on the dbuf: per-step all-gather bounds inter-block skew to <1 iteration.
__global__ __launch_bounds__(256, 1) void lstm_persist(
    float* __restrict__ ws,
    const int* __restrict__ x, const int* __restrict__ mask,
    const float* __restrict__ embed)
{
    __shared__ float comb_lds[8 * K];                    // 24 KB
    __shared__ float part2_lds[8 * 8 * 64];              // 16 KB: [s8][q=0..8][row 0..64]

    const int bid = blockIdx.x;
    const int rg  = bid >> 3, sg = bid & 7;
    const int tid = threadIdx.x;
    const int w   = tid >> 6, l = tid & 63;
    const int half = l >> 5, rl = l & 31;                // GEMV: lane covers rows 2rl,2rl+1
    const int seq_base = sg * 8;
    const int gate = l & 3, qlane = l >> 2;              // reduce: lane l owns row rg*64+l

    const float4* WT4 = (const float4*)(ws + OFF_WT4);
    const float*  bI  = ws + OFF_BI;
    unsigned long long* comb2 = (unsigned long long*)(ws + OFF_COMB2);
    float* repg = ws + OFF_REP;

    // ---- stationary weights: single array, const indices (AGPR promotion!)
    // wreg[j] = row (rg*64+2rl), wreg[24+j] = row (rg*64+2rl+1), k4 = w*48+half*24+j
    float4 wreg[48];
    {
        const int kb   = w * 48 + half * 24;
        const int rowA = rg * 64 + 2 * rl;
        #pragma unroll
        for (int j = 0; j < 24; ++j) {
            wreg[j]      = WT4[(size_t)(kb + j) * ROWS + rowA];
            wreg[24 + j] = WT4[(size_t)(kb + j) * ROWS + rowA + 1];
        }
    }
    const float breg = bI[rg * 64 + l];                  // bias for the REDUCE row

    // ---- per-owner-lane state (lanes with gate==0), 2 phases: seqs w and w+4
    float c0 = 0.f, c1 = 0.f, h0 = 0.f, h1 = 0.f, r0 = 0.f, r1 = 0.f;

    const int sl = tid >> 5, col = (tid & 31) * 8;       // emb gather mapping

    // ---- prologue: slot0 = [emb(t=0) | h=0], everything tagged 1
    if (gate == 0) {
        unsigned long long z = ((unsigned long long)1u << 32); // (0.0f, tag 1)
        __hip_atomic_store(&comb2[(size_t)(seq_base + w)     * K + E + rg * 16 + qlane],
                           z, __ATOMIC_RELAXED, __HIP_MEMORY_SCOPE_AGENT);
        __hip_atomic_store(&comb2[(size_t)(seq_base + w + 4) * K + E + rg * 16 + qlane],
                           z, __ATOMIC_RELAXED, __HIP_MEMORY_SCOPE_AGENT);
    }
    if (rg == 0) {
        int tok = x[(size_t)(seq_base + sl) * L + 0];
        const float* er = embed + (size_t)tok * E + col;
        float4 a = *(const float4*)er, b = *(const float4*)(er + 4);
        unsigned long long* dst = comb2 + (size_t)(seq_base + sl) * K + col;
        #pragma unroll
        for (int j = 0; j < 8; ++j) {
            float v = (j < 4) ? ((const float*)&a)[j] : ((const float*)&b)[j - 4];
            unsigned long long p = ((unsigned long long)1u << 32)
                                 | (unsigned long long)__float_as_uint(v);
            __hip_atomic_store(&dst[j], p, __ATOMIC_RELAXED, __HIP_MEMORY_SCOPE_AGENT);
        }
    }

    // ---- main recurrence: 2 barriers per step, zero flags, zero fences
    for (int t = 0; t < L; ++t) {
        const unsigned long long* c2c = comb2 + (size_t)(t & 1) * B * K
                                              + (size_t)seq_base * K;
        unsigned long long*       c2n = comb2 + (size_t)((t + 1) & 1) * B * K
                                              + (size_t)seq_base * K;

        // (a) issue emb loads for t+1 early (read-only, independent of sync)
        float4 e0, e1;
        const bool pf = (rg == 0) && ((t + 1) < L);
        if (pf) {
            int tok = x[(size_t)(seq_base + sl) * L + (t + 1)];
            const float* er = embed + (size_t)tok * E + col;
            e0 = *(const float4*)er;
            e1 = *(const float4*)(er + 4);
        }

        // (b) tagged staging-poll: pairs of u64 -> one ds_write_b64 each
        {
            const unsigned int want = (unsigned int)(t + 1);
            int guard = 0;
            for (;;) {
                bool ok = true;
                #pragma unroll
                for (int i = 0; i < 12; ++i) {
                    int idx = i * 512 + tid * 2;         // u64 idx, 8B-pair aligned
                    unsigned long long v0 = __hip_atomic_load(
                        &c2c[idx], __ATOMIC_RELAXED, __HIP_MEMORY_SCOPE_AGENT);
                    unsigned long long v1 = __hip_atomic_load(
                        &c2c[idx + 1], __ATOMIC_RELAXED, __HIP_MEMORY_SCOPE_AGENT);
                    *(float2*)&comb_lds[idx] = make_float2(
                        __uint_as_float((unsigned int)v0),
                        __uint_as_float((unsigned int)v1));
                    ok &= ((unsigned int)(v0 >> 32) == want)
                        & ((unsigned int)(v1 >> 32) == want);
                }
                if (__all(ok) || ++guard > (1 << 20)) break;
                __builtin_amdgcn_s_sleep(2);
            }
        }

        // (c) rg0: land pre-gathered emb for t+1 (tagged t+2, single atomic each)
        if (pf) {
            unsigned long long* dst = c2n + (size_t)sl * K + col;
            const unsigned long long hi = ((unsigned long long)(unsigned int)(t + 2)) << 32;
            #pragma unroll
            for (int j = 0; j < 8; ++j) {
                float v = (j < 4) ? ((const float*)&e0)[j] : ((const float*)&e1)[j - 4];
                __hip_atomic_store(&dst[j], hi | (unsigned long long)__float_as_uint(v),
                                   __ATOMIC_RELAXED, __HIP_MEMORY_SCOPE_AGENT);
            }
        }
        __syncthreads();                                 // S1: comb_lds ready

        // (d) GEMV: 2 rows/lane, one b128 broadcast feeds 8 FMAs
        float accA[8] = {0.f, 0.f, 0.f, 0.f, 0.f, 0.f, 0.f, 0.f};
        float accB[8] = {0.f, 0.f, 0.f, 0.f, 0.f, 0.f, 0.f, 0.f};
        const float* clbase = comb_lds + (w * 48 + half * 24) * 4;
        #pragma unroll
        for (int j = 0; j < 24; ++j) {
            float4 wa = wreg[j], wb = wreg[24 + j];
            #pragma unroll
            for (int s8 = 0; s8 < 8; ++s8) {
                float4 c4 = *(const float4*)(clbase + s8 * K + j * 4); // 2-addr broadcast
                accA[s8] = fmaf(wa.x, c4.x, accA[s8]);
                accA[s8] = fmaf(wa.y, c4.y, accA[s8]);
                accA[s8] = fmaf(wa.z, c4.z, accA[s8]);
                accA[s8] = fmaf(wa.w, c4.w, accA[s8]);
                accB[s8] = fmaf(wb.x, c4.x, accB[s8]);
                accB[s8] = fmaf(wb.y, c4.y, accB[s8]);
                accB[s8] = fmaf(wb.z, c4.z, accB[s8]);
                accB[s8] = fmaf(wb.w, c4.w, accB[s8]);
            }
        }
        // write both rows' partials with one ds_write_b64 per s8
        #pragma unroll
        for (int s8 = 0; s8 < 8; ++s8) {
            *(float2*)&part2_lds[(s8 * 8 + (w * 2 + half)) * 64 + 2 * rl] =
                make_float2(accA[s8], accB[s8]);
        }
        __syncthreads();                                 // S2

        // (e) reduce 8 k-slices, activations (DPP quad-broadcast, off LDS pipe),
        //     c/h update (2 phases: seq = p*4 + w); lane l owns row rg*64+l
        #pragma unroll
        for (int p = 0; p < 2; ++p) {
            int s8 = p * 4 + w;
            float a = breg;
            #pragma unroll
            for (int q = 0; q < 8; ++q)
                a += part2_lds[(s8 * 8 + q) * 64 + l];
            float act = (gate == 2) ? tanhf(a) : 1.f / (1.f + expf(-a));
            int ab = __float_as_int(act);
            float fg = __int_as_float(__builtin_amdgcn_mov_dpp(ab, 0x00, 0xF, 0xF, true));
            float ig = __int_as_float(__builtin_amdgcn_mov_dpp(ab, 0x55, 0xF, 0xF, true));
            float cg = __int_as_float(__builtin_amdgcn_mov_dpp(ab, 0xAA, 0xF, 0xF, true));
            float og = __int_as_float(__builtin_amdgcn_mov_dpp(ab, 0xFF, 0xF, 0xF, true));
            if (gate == 0) {
                float& cr = p ? c1 : c0;
                float& hr = p ? h1 : h0;
                float& rr = p ? r1 : r0;
                cr = fg * cr + ig * cg;                  // c not mask-blended (matches ref)
                float hn = og * tanhf(cr);
                int seq = seq_base + s8;
                float m = (mask[(size_t)seq * L + t] != 0) ? 1.f : 0.f;
                float h = hn * m + hr * (1.f - m);
                hr = h;
                // single 8B atomic carries value AND readiness -> no release needed
                unsigned long long p64 = (((unsigned long long)(unsigned int)(t + 2)) << 32)
                                       | (unsigned long long)__float_as_uint(h);
                __hip_atomic_store(&c2n[(size_t)s8 * K + E + rg * 16 + qlane],
                                   p64, __ATOMIC_RELAXED, __HIP_MEMORY_SCOPE_AGENT);
                rr += h * m;
            }
        }
        // NO S3, NO flag store: next iteration's poll is the only consumer-side gate.
    }

    // ---- epilogue: dump rep registers (unique owner per (seq,unit))
    if (gate == 0) {
        repg[(size_t)(seq_base + w)     * H + rg * 16 + qlane] = r0;
        repg[(size_t)(seq_base + w + 4) * H + rg * 16 + qlane] = r1;
    }
}

// ---------------- final: rep mean + logits ----------------
__global__ __launch_bounds__(256) void lstm_final(
    const float* __restrict__ ws,
    const int* __restrict__ mask,
    const float* __restrict__ Wfc, const float* __restrict__ bfc,
    float* __restrict__ out)
{
    __shared__ float sred[256];
    __shared__ float srep[H];
    int s = blockIdx.x, tid = threadIdx.x;

    float dsum = 0.f;
    for (int i = tid; i < L; i += 256) dsum += (mask[(size_t)s * L + i] != 0) ? 1.f : 0.f;
    sred[tid] = dsum; __syncthreads();
    for (int off = 128; off > 0; off >>= 1) {
        if (tid < off) sred[tid] += sred[tid + off];
        __syncthreads();
    }
    float denom = fmaxf(sred[0], 1e-9f);
    __syncthreads();

    const float* repa = ws + OFF_REP + (size_t)s * H;
    for (int i = tid; i < H; i += 256) {
        float r = repa[i] / denom;
        srep[i] = r;
        out[128 + (size_t)s * H + i] = r;
    }
    __syncthreads();

    for (int c = 0; c < 2; ++c) {
        float d = 0.f;
        for (int i = tid; i < H; i += 256) d += srep[i] * Wfc[(size_t)c * H + i];
        sred[tid] = d; __syncthreads();
        for (int off = 128; off > 0; off >>= 1) {
            if (tid < off) sred[tid] += sred[tid + off];
            __syncthreads();
        }
        if (tid == 0) out[(size_t)s * 2 + c] = sred[0] + bfc[c];
        __syncthreads();
    }
}

// ---------------- host ----------------
extern "C" void kernel_launch(void* const* d_in, const int* in_sizes, int n_in,
                              void* d_out, int out_size, void* d_ws, size_t ws_size,
                              hipStream_t stream)
{
    const int*   x     = (const int*)d_in[0];
    const int*   mask  = (const int*)d_in[1];
    const float* embed = (const float*)d_in[2];
    const float* Wf = (const float*)d_in[3];  const float* bf = (const float*)d_in[4];
    const float* Wi = (const float*)d_in[5];  const float* bi = (const float*)d_in[6];
    const float* Wc = (const float*)d_in[7];  const float* bc = (const float*)d_in[8];
    const float* Wo = (const float*)d_in[9];  const float* bo = (const float*)d_in[10];
    const float* Wfc = (const float*)d_in[11]; const float* bfc = (const float*)d_in[12];
    float* out = (float*)d_out;
    float* ws  = (float*)d_ws;

    if (ws_size < WS_FLOATS * sizeof(float)) {
        return; // leave output poisoned so the failure mode is unambiguous
    }

    prep_weights<<<256, 256, 0, stream>>>(Wf, Wi, Wc, Wo, bf, bi, bc, bo, ws);
    lstm_persist<<<256, 256, 0, stream>>>(ws, x, mask, embed);
    lstm_final<<<64, 256, 0, stream>>>(ws, mask, Wfc, bfc, out);
}

// Round 5
// 2563.272 us; speedup vs baseline: 5.3008x; 1.7689x over previous
//
#include <hip/hip_runtime.h>

// ---------------- problem constants ----------------
constexpr int B = 64, L = 512, E = 256, H = 512;
constexpr int ROWS = 4 * H;      // 2048 gate-rows (unit*4 + gate interleave)
constexpr int K    = E + H;      // 768
constexpr int K4   = K / 4;      // 192

// ---------------- ws layout (in floats) ----------------
constexpr size_t OFF_WT4   = 0;
constexpr size_t SZ_WT4    = (size_t)K4 * ROWS * 4;     // float4[K4][ROWS]
constexpr size_t OFF_BI    = OFF_WT4 + SZ_WT4;          // interleaved biases [ROWS]
constexpr size_t SZ_BI     = ROWS;
constexpr size_t OFF_H2    = OFF_BI + SZ_BI;            // TAGGED h dbuf [2][B][H] x (val,tag)
constexpr size_t SZ_H2     = (size_t)2 * B * H * 2;     // in floats (u64 per element)
constexpr size_t OFF_REP   = OFF_H2 + SZ_H2;            // rep accumulator [B][H]
constexpr size_t SZ_REP    = (size_t)B * H;
constexpr size_t WS_FLOATS = OFF_REP + SZ_REP;

// ---------------- prep: transpose + interleave weights, invalidate h tags ----------------
__global__ __launch_bounds__(256) void prep_weights(
    const float* __restrict__ Wf, const float* __restrict__ Wi,
    const float* __restrict__ Wc, const float* __restrict__ Wo,
    const float* __restrict__ bf, const float* __restrict__ bi,
    const float* __restrict__ bc, const float* __restrict__ bo,
    float* __restrict__ ws)
{
    float* WT4 = ws + OFF_WT4;
    float* bI  = ws + OFF_BI;
    int idx = blockIdx.x * 256 + threadIdx.x;            // 65536 threads
    const float* Ws[4] = {Wf, Wi, Wc, Wo};
    #pragma unroll
    for (int j = 0; j < 6; ++j) {
        int item = idx + j * 65536;                      // [0, 393216)
        int k4   = item >> 11;                           // /2048
        int row  = item & 2047;
        int unit = row >> 2, gate = row & 3;
        const float* W = Ws[gate];
        float4 v = *(const float4*)(W + (size_t)unit * K + (size_t)k4 * 4);
        *(float4*)(WT4 + ((size_t)k4 * ROWS + row) * 4) = v;
    }
    if (idx < ROWS) {
        int unit = idx >> 2, gate = idx & 3;
        const float* bs[4] = {bf, bi, bc, bo};
        bI[idx] = bs[gate][unit];
    }
    // zero all tags (tag 0 matches no want >= 2); end-of-dispatch L2 writeback makes
    // these visible to persist's sc-bypass loads (validated R2/R3/R4).
    ((unsigned long long*)(ws + OFF_H2))[idx] = 0ull;    // 2*B*H = 65536 u64 exactly
}

// ---------------- persistent LSTM kernel ----------------
// grid 256 = 32 row-groups x 8 seq-groups; bid = rg*8 + sg.
// block 256 thr = 4 waves; wave w, lane l: q = l>>4, rl = l&15, m = w*4+q (0..15).
//
// R5 GEMV geometry (LDS return-bus theory, R4-validated): 4 rows/lane x 12 k4 --
// one ds_read_b128 broadcast feeds 16 FMAs. Lane covers rows rg*64+4rl..+3;
// E k4 = w*16 + q + 4*jj (jj<4), H k4 = 64 + w*32 + q + 4*jj (jj<8) -- the q
// interleave keeps the 4 quarter-group addresses in disjoint banks.
//
// E/H split: embeddings are pure functions of read-only x/embed -> gathered
// LOCALLY per block (L2-cached), never shipped through LLC. Tagged LLC payload
// is h only (32 KB/block/step, was 48). E-GEMV runs between tagged-load issue
// and tag check, hiding the LLC round trip + detect lag.
//
// REGISTER RULE (R1 failure): weights live in ONE wreg[48] float4 array with
// constant indices (E=[0..15], H=[16..47]) -> AGPR promotion. Splitting the
// array spilled 25 GB to scratch.
//
// Cross-block protocol = R3/R4's tagged scheme: each h element is an 8-byte
// atomic (f32 value, u32 tag); producers store (h, t+2) with one relaxed
// agent-scope store; consumers' staging load IS the poll (retry until
// __all(tags == t+1)). WAR on the dbuf: per-step all-gather bounds skew <1 step.
__global__ __launch_bounds__(256, 1) void lstm_persist(
    float* __restrict__ ws,
    const int* __restrict__ x, const int* __restrict__ mask,
    const float* __restrict__ embed)
{
    __shared__ float emb_lds[2][8][E];                   // 16 KB dbuf (local gather)
    __shared__ float h_lds[8 * H];                       // 16 KB
    __shared__ float part2_lds[8 * 16 * 64];             // 32 KB: [s8][m=0..16][row]

    const int bid = blockIdx.x;
    const int rg  = bid >> 3, sg = bid & 7;
    const int tid = threadIdx.x;
    const int w   = tid >> 6, l = tid & 63;
    const int q   = l >> 4, rl = l & 15, m = w * 4 + q;  // GEMV mapping
    const int seq_base = sg * 8;
    const int gate = l & 3, qlane = l >> 2;              // reduce: lane l owns row rg*64+l

    const float4* WT4 = (const float4*)(ws + OFF_WT4);
    const float*  bI  = ws + OFF_BI;
    unsigned long long* h2 = (unsigned long long*)(ws + OFF_H2);
    float* repg = ws + OFF_REP;

    // ---- stationary weights: ONE array, const indices (AGPR promotion!)
    // E: wreg[r*4+jj] = WT4[w*16+q+4jj][rowA+r]; H: wreg[16+r*8+jj] = WT4[64+w*32+q+4jj][rowA+r]
    float4 wreg[48];
    {
        const int rowA = rg * 64 + rl * 4;
        #pragma unroll
        for (int jj = 0; jj < 4; ++jj)
            #pragma unroll
            for (int r = 0; r < 4; ++r)
                wreg[r * 4 + jj] = WT4[(size_t)(w * 16 + q + 4 * jj) * ROWS + rowA + r];
        #pragma unroll
        for (int jj = 0; jj < 8; ++jj)
            #pragma unroll
            for (int r = 0; r < 4; ++r)
                wreg[16 + r * 8 + jj] = WT4[(size_t)(64 + w * 32 + q + 4 * jj) * ROWS + rowA + r];
    }
    const float breg = bI[rg * 64 + l];                  // bias for the REDUCE row

    // ---- per-owner-lane state (lanes with gate==0), 2 phases: seqs w and w+4
    float c0 = 0.f, c1 = 0.f, h0 = 0.f, h1 = 0.f, r0 = 0.f, r1 = 0.f;

    const int sl = tid >> 5, col = (tid & 31) * 8;       // emb gather mapping

    // ---- prologue: local emb gather for t=0; h_lds = 0 (no poll at t=0)
    {
        int tok = x[(size_t)(seq_base + sl) * L + 0];
        const float* er = embed + (size_t)tok * E + col;
        *(float4*)&emb_lds[0][sl][col]     = *(const float4*)er;
        *(float4*)&emb_lds[0][sl][col + 4] = *(const float4*)(er + 4);
        #pragma unroll
        for (int i = 0; i < 16; ++i) h_lds[tid + i * 256] = 0.f;
    }
    __syncthreads();

    // ---- main recurrence: 2 barriers per step, zero flags, zero fences
    for (int t = 0; t < L; ++t) {
        const int cur = t & 1, nxt = cur ^ 1;
        const unsigned long long* c2c = h2 + (size_t)cur * B * H + (size_t)seq_base * H;
        unsigned long long*       c2n = h2 + (size_t)nxt * B * H + (size_t)seq_base * H;

        // (a) local emb prefetch for t+1 (plain cached loads, read-only data)
        float4 e0, e1;
        const bool pf = (t + 1) < L;
        if (pf) {
            int tok = x[(size_t)(seq_base + sl) * L + (t + 1)];
            const float* er = embed + (size_t)tok * E + col;
            e0 = *(const float4*)er;
            e1 = *(const float4*)(er + 4);
        }

        // (b) issue tagged h loads (16 u64/thread); tag check deferred past E-GEMV
        unsigned long long hv[16];
        if (t > 0) {
            #pragma unroll
            for (int i = 0; i < 8; ++i) {
                hv[2 * i]     = __hip_atomic_load(&c2c[i * 512 + tid * 2],
                                    __ATOMIC_RELAXED, __HIP_MEMORY_SCOPE_AGENT);
                hv[2 * i + 1] = __hip_atomic_load(&c2c[i * 512 + tid * 2 + 1],
                                    __ATOMIC_RELAXED, __HIP_MEMORY_SCOPE_AGENT);
            }
        }

        // (c) E-GEMV while tagged loads fly: 512 FMAs, 1 b128 per 16 FMAs
        float acc[4][8];
        #pragma unroll
        for (int r = 0; r < 4; ++r)
            #pragma unroll
            for (int s8 = 0; s8 < 8; ++s8) acc[r][s8] = 0.f;
        #pragma unroll
        for (int jj = 0; jj < 4; ++jj) {
            const int off = (w * 16 + q + 4 * jj) * 4;
            #pragma unroll
            for (int s8 = 0; s8 < 8; ++s8) {
                float4 c4 = *(const float4*)&emb_lds[cur][s8][off];
                #pragma unroll
                for (int r = 0; r < 4; ++r) {
                    float4 wv = wreg[r * 4 + jj];
                    acc[r][s8] = fmaf(wv.x, c4.x, acc[r][s8]);
                    acc[r][s8] = fmaf(wv.y, c4.y, acc[r][s8]);
                    acc[r][s8] = fmaf(wv.z, c4.z, acc[r][s8]);
                    acc[r][s8] = fmaf(wv.w, c4.w, acc[r][s8]);
                }
            }
        }

        // (d) verify tags (retry rare), land h into LDS
        if (t > 0) {
            const unsigned int want = (unsigned int)(t + 1);
            int guard = 0;
            for (;;) {
                bool ok = true;
                #pragma unroll
                for (int i = 0; i < 16; ++i)
                    ok &= ((unsigned int)(hv[i] >> 32) == want);
                if (__all(ok) || ++guard > (1 << 20)) break;
                __builtin_amdgcn_s_sleep(2);
                #pragma unroll
                for (int i = 0; i < 8; ++i) {
                    hv[2 * i]     = __hip_atomic_load(&c2c[i * 512 + tid * 2],
                                        __ATOMIC_RELAXED, __HIP_MEMORY_SCOPE_AGENT);
                    hv[2 * i + 1] = __hip_atomic_load(&c2c[i * 512 + tid * 2 + 1],
                                        __ATOMIC_RELAXED, __HIP_MEMORY_SCOPE_AGENT);
                }
            }
            #pragma unroll
            for (int i = 0; i < 8; ++i)
                *(float2*)&h_lds[i * 512 + tid * 2] = make_float2(
                    __uint_as_float((unsigned int)hv[2 * i]),
                    __uint_as_float((unsigned int)hv[2 * i + 1]));
        }

        // (e) land emb prefetch
        if (pf) {
            *(float4*)&emb_lds[nxt][sl][col]     = e0;
            *(float4*)&emb_lds[nxt][sl][col + 4] = e1;
        }
        __syncthreads();                                 // S1: h_lds/emb ready

        // (f) H-GEMV: 1024 FMAs, 1 b128 per 16 FMAs
        #pragma unroll
        for (int jj = 0; jj < 8; ++jj) {
            const int off = (w * 32 + q + 4 * jj) * 4;
            #pragma unroll
            for (int s8 = 0; s8 < 8; ++s8) {
                float4 c4 = *(const float4*)&h_lds[s8 * 512 + off];
                #pragma unroll
                for (int r = 0; r < 4; ++r) {
                    float4 wv = wreg[16 + r * 8 + jj];
                    acc[r][s8] = fmaf(wv.x, c4.x, acc[r][s8]);
                    acc[r][s8] = fmaf(wv.y, c4.y, acc[r][s8]);
                    acc[r][s8] = fmaf(wv.z, c4.z, acc[r][s8]);
                    acc[r][s8] = fmaf(wv.w, c4.w, acc[r][s8]);
                }
            }
        }
        // partials: one b128 per s8 (4 rows packed)
        #pragma unroll
        for (int s8 = 0; s8 < 8; ++s8) {
            float4 v = make_float4(acc[0][s8], acc[1][s8], acc[2][s8], acc[3][s8]);
            *(float4*)&part2_lds[(s8 * 16 + m) * 64 + rl * 4] = v;
        }
        __syncthreads();                                 // S2

        // (g) reduce 16 k-slices, activations (DPP quad-broadcast), c/h update
        #pragma unroll
        for (int p = 0; p < 2; ++p) {
            int s8 = p * 4 + w;
            float a = breg;
            #pragma unroll
            for (int mm = 0; mm < 16; ++mm)
                a += part2_lds[(s8 * 16 + mm) * 64 + l];
            float act = (gate == 2) ? tanhf(a) : 1.f / (1.f + expf(-a));
            int ab = __float_as_int(act);
            float fg = __int_as_float(__builtin_amdgcn_mov_dpp(ab, 0x00, 0xF, 0xF, true));
            float ig = __int_as_float(__builtin_amdgcn_mov_dpp(ab, 0x55, 0xF, 0xF, true));
            float cg = __int_as_float(__builtin_amdgcn_mov_dpp(ab, 0xAA, 0xF, 0xF, true));
            float og = __int_as_float(__builtin_amdgcn_mov_dpp(ab, 0xFF, 0xF, 0xF, true));
            if (gate == 0) {
                float& cr = p ? c1 : c0;
                float& hr = p ? h1 : h0;
                float& rr = p ? r1 : r0;
                cr = fg * cr + ig * cg;                  // c not mask-blended (matches ref)
                float hn = og * tanhf(cr);
                int seq = seq_base + s8;
                float mk = (mask[(size_t)seq * L + t] != 0) ? 1.f : 0.f;
                float h = hn * mk + hr * (1.f - mk);
                hr = h;
                // single 8B atomic carries value AND readiness -> no release needed
                unsigned long long p64 = (((unsigned long long)(unsigned int)(t + 2)) << 32)
                                       | (unsigned long long)__float_as_uint(h);
                __hip_atomic_store(&c2n[(size_t)s8 * H + rg * 16 + qlane],
                                   p64, __ATOMIC_RELAXED, __HIP_MEMORY_SCOPE_AGENT);
                rr += h * mk;
            }
        }
        // NO S3: next iteration's tag check is the only consumer-side gate.
    }

    // ---- epilogue: dump rep registers (unique owner per (seq,unit))
    if (gate == 0) {
        repg[(size_t)(seq_base + w)     * H + rg * 16 + qlane] = r0;
        repg[(size_t)(seq_base + w + 4) * H + rg * 16 + qlane] = r1;
    }
}

// ---------------- final: rep mean + logits ----------------
__global__ __launch_bounds__(256) void lstm_final(
    const float* __restrict__ ws,
    const int* __restrict__ mask,
    const float* __restrict__ Wfc, const float* __restrict__ bfc,
    float* __restrict__ out)
{
    __shared__ float sred[256];
    __shared__ float srep[H];
    int s = blockIdx.x, tid = threadIdx.x;

    float dsum = 0.f;
    for (int i = tid; i < L; i += 256) dsum += (mask[(size_t)s * L + i] != 0) ? 1.f : 0.f;
    sred[tid] = dsum; __syncthreads();
    for (int off = 128; off > 0; off >>= 1) {
        if (tid < off) sred[tid] += sred[tid + off];
        __syncthreads();
    }
    float denom = fmaxf(sred[0], 1e-9f);
    __syncthreads();

    const float* repa = ws + OFF_REP + (size_t)s * H;
    for (int i = tid; i < H; i += 256) {
        float r = repa[i] / denom;
        srep[i] = r;
        out[128 + (size_t)s * H + i] = r;
    }
    __syncthreads();

    for (int c = 0; c < 2; ++c) {
        float d = 0.f;
        for (int i = tid; i < H; i += 256) d += srep[i] * Wfc[(size_t)c * H + i];
        sred[tid] = d; __syncthreads();
        for (int off = 128; off > 0; off >>= 1) {
            if (tid < off) sred[tid] += sred[tid + off];
            __syncthreads();
        }
        if (tid == 0) out[(size_t)s * 2 + c] = sred[0] + bfc[c];
        __syncthreads();
    }
}

// ---------------- host ----------------
extern "C" void kernel_launch(void* const* d_in, const int* in_sizes, int n_in,
                              void* d_out, int out_size, void* d_ws, size_t ws_size,
                              hipStream_t stream)
{
    const int*   x     = (const int*)d_in[0];
    const int*   mask  = (const int*)d_in[1];
    const float* embed = (const float*)d_in[2];
    const float* Wf = (const float*)d_in[3];  const float* bf = (const float*)d_in[4];
    const float* Wi = (const float*)d_in[5];  const float* bi = (const float*)d_in[6];
    const float* Wc = (const float*)d_in[7];  const float* bc = (const float*)d_in[8];
    const float* Wo = (const float*)d_in[9];  const float* bo = (const float*)d_in[10];
    const float* Wfc = (const float*)d_in[11]; const float* bfc = (const float*)d_in[12];
    float* out = (float*)d_out;
    float* ws  = (float*)d_ws;

    if (ws_size < WS_FLOATS * sizeof(float)) {
        return; // leave output poisoned so the failure mode is unambiguous
    }

    prep_weights<<<256, 256, 0, stream>>>(Wf, Wi, Wc, Wo, bf, bi, bc, bo, ws);
    lstm_persist<<<256, 256, 0, stream>>>(ws, x, mask, embed);
    lstm_final<<<64, 256, 0, stream>>>(ws, mask, Wfc, bfc, out);
}